// Round 12
// baseline (1713.024 us; speedup 1.0000x reference)
//
#include <hip/hip_runtime.h>
#include <cstdint>
#include <cstddef>

#define DMODEL 512
#define NHEAD 8
#define HD 64

typedef float f32x4 __attribute__((ext_vector_type(4)));
typedef _Float16 f16x8 __attribute__((ext_vector_type(8)));
typedef _Float16 f16x4 __attribute__((ext_vector_type(4)));

// ---------------------------------------------------------------- threefry
__device__ __forceinline__ uint32_t rotl32(uint32_t x, int r) {
  return (x << r) | (x >> (32 - r));
}

__device__ __forceinline__ void tf_block(uint32_t k0, uint32_t k1,
                                         uint32_t& x0, uint32_t& x1) {
  uint32_t ks0 = k0, ks1 = k1, ks2 = k0 ^ k1 ^ 0x1BD11BDAu;
  x0 += ks0; x1 += ks1;
  x0 += x1; x1 = rotl32(x1, 13); x1 ^= x0;
  x0 += x1; x1 = rotl32(x1, 15); x1 ^= x0;
  x0 += x1; x1 = rotl32(x1, 26); x1 ^= x0;
  x0 += x1; x1 = rotl32(x1, 6);  x1 ^= x0;
  x0 += ks1; x1 += ks2 + 1u;
  x0 += x1; x1 = rotl32(x1, 17); x1 ^= x0;
  x0 += x1; x1 = rotl32(x1, 29); x1 ^= x0;
  x0 += x1; x1 = rotl32(x1, 16); x1 ^= x0;
  x0 += x1; x1 = rotl32(x1, 24); x1 ^= x0;
  x0 += ks2; x1 += ks0 + 2u;
  x0 += x1; x1 = rotl32(x1, 13); x1 ^= x0;
  x0 += x1; x1 = rotl32(x1, 15); x1 ^= x0;
  x0 += x1; x1 = rotl32(x1, 26); x1 ^= x0;
  x0 += x1; x1 = rotl32(x1, 6);  x1 ^= x0;
  x0 += ks0; x1 += ks1 + 3u;
  x0 += x1; x1 = rotl32(x1, 17); x1 ^= x0;
  x0 += x1; x1 = rotl32(x1, 29); x1 ^= x0;
  x0 += x1; x1 = rotl32(x1, 16); x1 ^= x0;
  x0 += x1; x1 = rotl32(x1, 24); x1 ^= x0;
  x0 += ks1; x1 += ks2 + 4u;
  x0 += x1; x1 = rotl32(x1, 13); x1 ^= x0;
  x0 += x1; x1 = rotl32(x1, 15); x1 ^= x0;
  x0 += x1; x1 = rotl32(x1, 26); x1 ^= x0;
  x0 += x1; x1 = rotl32(x1, 6);  x1 ^= x0;
  x0 += ks2; x1 += ks0 + 5u;
}

__global__ void idx_kernel(int* __restrict__ idxb, int n, int layer, int mask) {
  int e = blockIdx.x * 256 + threadIdx.x;
  if (e >= n) return;
  uint32_t f0 = 0u, f1 = (uint32_t)layer;
  tf_block(0u, 42u, f0, f1);
  uint32_t s0 = 0u, s1 = 1u;
  tf_block(f0, f1, s0, s1);
  uint32_t x0 = 0u, x1 = (uint32_t)e;
  tf_block(s0, s1, x0, x1);
  uint32_t bits = x0 ^ x1;
  idxb[e] = (int)(bits & (uint32_t)mask);
}

// ---------------------------------------------------------------- GEMM 128x128 MFMA (fp16 split emulation of fp32)
// PREC=3: acc += Ah*Wh + Ah*Wl + Al*Wh (rel err ~2^-23).
// PREC=1: acc += Ah*Wh only (rel err ~2^-11) -- FFN/conv/V paths.
// FUSE3: N=1536 fused QKV; C-write selects {C,C2,C3} by column group.
//   V group (col0>=1024) runs lo=false at runtime: 1 product (V is a
//   continuous path); Q/K groups stay full PREC=3 -> top-k bit-identical.
// AF16: A is _Float16 (hi plane only; implies PREC=1 math). Numerically
//   identical to fp32-A PREC=1 (staging rounds A to f16-hi anyway).
// OF16: C stored as _Float16 (RNE) -- pairs with a downstream AF16 consumer.
// PART: block kb writes raw fp32 partial over K-slice into Cpart.
// CONV: logical A[r][k] = x[bbase + ((t-1+w)&Lmask)][k&511], w=k>>9 (fp32 A).
__device__ __forceinline__ float gelu_f(float v) {
  return 0.5f * v * (1.0f + erff(v * 0.7071067811865476f));
}

template <int ACT, int HASR, int CONV, int PART, int PREC, int FUSE3, int AF16,
          int OF16>
__global__ __launch_bounds__(256, 2) void gemm128(
    const void* __restrict__ A, const void* __restrict__ Wsp,
    const float* __restrict__ bias, const float* Rres, float* C, float* C2,
    float* C3, int N, int K, int Lmask, int ntx, int nty, int kloop, int ks) {
  // planes: 0=Ah 1=Al 2=Wh 3=Wl ; [row][k], k-slot (8 elems = 16B) XOR-swizzled
  __shared__ __align__(16) _Float16 sm[4][128][32];
  const _Float16* Wh = (const _Float16*)Wsp;
  const _Float16* Wl = Wh + (size_t)N * K;
  const float* Afp = (const float*)A;
  const _Float16* Af16 = (const _Float16*)A;
  const int tid = threadIdx.x;
  int blk = blockIdx.x;
  const int tiles = ntx * nty;
  int kb = 0;
  if (PART) { kb = blk / tiles; blk -= kb * tiles; }
  const int koff = kb * kloop;
  const int xcd = blk & 7;
  const int j = blk >> 3;
  const int jr = j / ntx;
  const int row_t = xcd * (nty >> 3) + jr;
  const int col_t = j - jr * ntx;
  const int row0 = row_t * 128, col0 = col_t * 128;

  // lo: whether the 2 low-order products run (block-uniform)
  const bool lo = (PREC == 3) && !(FUSE3 && col0 >= 1024);

  const int r4 = tid >> 2;  // 0..63
  const int ss = tid & 3;   // k-slot (8 fp32 / 8 halves)

  const size_t aoff0 = (size_t)(row0 + r4) * K + koff + ss * 8;
  const size_t aoff1 = (size_t)(row0 + 64 + r4) * K + koff + ss * 8;
  const _Float16* Wh0 = Wh + (size_t)(col0 + r4) * K + koff + ss * 8;
  const _Float16* Wh1 = Wh + (size_t)(col0 + 64 + r4) * K + koff + ss * 8;
  const _Float16* Wl0 = Wl + (size_t)(col0 + r4) * K + koff + ss * 8;
  const _Float16* Wl1 = Wl + (size_t)(col0 + 64 + r4) * K + koff + ss * 8;
  int tcv0 = 0, bb0 = 0, tcv1 = 0, bb1 = 0;
  if (CONV) {
    int a0 = row0 + r4, a1 = row0 + 64 + r4;
    tcv0 = a0 & Lmask; bb0 = a0 & ~Lmask;
    tcv1 = a1 & Lmask; bb1 = a1 & ~Lmask;
  }

  // wave -> 64x64 sub-tile; 4x4 frags of 16x16, K=32 per MFMA
  const int lane = tid & 63;
  const int wv = tid >> 6;
  const int wr = (wv >> 1) << 6;
  const int wc = (wv & 1) << 6;
  const int fr = lane & 15;  // frag row (A) / col (B)
  const int fs = lane >> 4;  // frag k-slot

  f32x4 acc[4][4];
  {
    f32x4 z = {0.f, 0.f, 0.f, 0.f};
#pragma unroll
    for (int r = 0; r < 4; ++r)
#pragma unroll
      for (int c = 0; c < 4; ++c) acc[r][c] = z;
  }

  f32x4 ra[4], rwh[2], rwl[2];
  f16x8 rah[2];

  auto gload = [&](int k0) {
    if (AF16) {
      rah[0] = *(const f16x8*)(Af16 + aoff0 + k0);
      rah[1] = *(const f16x8*)(Af16 + aoff1 + k0);
    } else if (CONV) {
      int kabs = koff + k0 + ss * 8;
      int w = kabs >> 9, cq = kabs & 511;
      const float* a0p =
          Afp + (size_t)(bb0 | ((tcv0 - 1 + w) & Lmask)) * 512 + cq;
      const float* a1p =
          Afp + (size_t)(bb1 | ((tcv1 - 1 + w) & Lmask)) * 512 + cq;
      ra[0] = *(const f32x4*)(a0p);
      ra[1] = *(const f32x4*)(a0p + 4);
      ra[2] = *(const f32x4*)(a1p);
      ra[3] = *(const f32x4*)(a1p + 4);
    } else {
      ra[0] = *(const f32x4*)(Afp + aoff0 + k0);
      ra[1] = *(const f32x4*)(Afp + aoff0 + k0 + 4);
      ra[2] = *(const f32x4*)(Afp + aoff1 + k0);
      ra[3] = *(const f32x4*)(Afp + aoff1 + k0 + 4);
    }
    rwh[0] = *(const f32x4*)(Wh0 + k0);
    rwh[1] = *(const f32x4*)(Wh1 + k0);
    if (PREC == 3) {
      if (lo) {
        rwl[0] = *(const f32x4*)(Wl0 + k0);
        rwl[1] = *(const f32x4*)(Wl1 + k0);
      }
    }
  };

  const int T = kloop >> 5;  // BK = 32
  gload(0);

  for (int it = 0; it < T; ++it) {
    // stage regs -> LDS (A: fp32 -> f16 hi(/lo) split, or f16 copy; W: copy)
#pragma unroll
    for (int p = 0; p < 2; ++p) {
      const int row = (p << 6) + r4;
      const int sl = (ss ^ ((row >> 1) & 3)) << 3;  // swizzled slot base
      if (AF16) {
        *(f16x8*)&sm[0][row][sl] = rah[p];
      } else {
        float tmp[8];
        *(f32x4*)(tmp) = ra[2 * p];
        *(f32x4*)(tmp + 4) = ra[2 * p + 1];
        _Float16 hv[8], lv[8];
#pragma unroll
        for (int q = 0; q < 8; ++q) {
          _Float16 h = (_Float16)tmp[q];
          hv[q] = h;
          if (PREC == 3) lv[q] = (_Float16)(tmp[q] - (float)h);
        }
        *(f16x8*)&sm[0][row][sl] = *(f16x8*)hv;
        if (PREC == 3) {
          if (lo) *(f16x8*)&sm[1][row][sl] = *(f16x8*)lv;
        }
      }
      *(f32x4*)&sm[2][row][sl] = rwh[p];
      if (PREC == 3) {
        if (lo) *(f32x4*)&sm[3][row][sl] = rwl[p];
      }
    }
    __syncthreads();
    if (it + 1 < T) gload((it + 1) << 5);  // prefetch overlaps MFMA below
    // fragments
    f16x8 wfh[4], wfl[4], afh[4], afl[4];
#pragma unroll
    for (int c = 0; c < 4; ++c) {
      const int row = wc + (c << 4) + fr;
      const int sl = (fs ^ ((row >> 1) & 3)) << 3;
      wfh[c] = *(const f16x8*)&sm[2][row][sl];
      if (PREC == 3) {
        if (lo) wfl[c] = *(const f16x8*)&sm[3][row][sl];
      }
    }
#pragma unroll
    for (int r = 0; r < 4; ++r) {
      const int row = wr + (r << 4) + fr;
      const int sl = (fs ^ ((row >> 1) & 3)) << 3;
      afh[r] = *(const f16x8*)&sm[0][row][sl];
      if (PREC == 3) {
        if (lo) afl[r] = *(const f16x8*)&sm[1][row][sl];
      }
    }
#pragma unroll
    for (int r = 0; r < 4; ++r)
#pragma unroll
      for (int c = 0; c < 4; ++c)
        acc[r][c] = __builtin_amdgcn_mfma_f32_16x16x32_f16(afh[r], wfh[c],
                                                           acc[r][c], 0, 0, 0);
    if (PREC == 3) {
      if (lo) {
#pragma unroll
        for (int r = 0; r < 4; ++r)
#pragma unroll
          for (int c = 0; c < 4; ++c) {
            acc[r][c] = __builtin_amdgcn_mfma_f32_16x16x32_f16(
                afh[r], wfl[c], acc[r][c], 0, 0, 0);
            acc[r][c] = __builtin_amdgcn_mfma_f32_16x16x32_f16(
                afl[r], wfh[c], acc[r][c], 0, 0, 0);
          }
      }
    }
    __syncthreads();
  }

  // C/D layout: col = lane&15, row = (lane>>4)*4 + reg
  const int crow = fs << 2;
  if (PART) {
    float* Cp = C + (size_t)kb * ((size_t)(nty << 7)) * N;
#pragma unroll
    for (int r = 0; r < 4; ++r) {
      const int m0 = row0 + wr + (r << 4) + crow;
#pragma unroll
      for (int c = 0; c < 4; ++c) {
        const int n0 = col0 + wc + (c << 4) + fr;
#pragma unroll
        for (int q = 0; q < 4; ++q)
          Cp[(size_t)(m0 + q) * N + n0] = acc[r][c][q];
      }
    }
  } else if (FUSE3) {
    const int grp = col0 >> 9;  // 0:Q 1:K 2:V (128 | 512, no straddle)
    float* Cb = (grp == 0) ? C : ((grp == 1) ? C2 : C3);
#pragma unroll
    for (int r = 0; r < 4; ++r) {
      const int m0 = row0 + wr + (r << 4) + crow;
#pragma unroll
      for (int c = 0; c < 4; ++c) {
        const int n0 = col0 + wc + (c << 4) + fr;  // bias index (concat 1536)
        const int cl = n0 & 511;                   // local col, ldc = 512
        const float bcol = bias[n0];
#pragma unroll
        for (int q = 0; q < 4; ++q)
          Cb[(size_t)(m0 + q) * 512 + cl] = acc[r][c][q] + bcol;
      }
    }
  } else {
#pragma unroll
    for (int r = 0; r < 4; ++r) {
      const int m0 = row0 + wr + (r << 4) + crow;
#pragma unroll
      for (int c = 0; c < 4; ++c) {
        const int n0 = col0 + wc + (c << 4) + fr;
        const float bcol = bias[n0];
#pragma unroll
        for (int q = 0; q < 4; ++q) {
          float v = acc[r][c][q] + bcol;
          if (HASR) v += Rres[(size_t)(m0 + q) * N + n0];
          if (ACT == 1) v = gelu_f(v);
          if (OF16) {
            ((_Float16*)C)[(size_t)(m0 + q) * N + n0] = (_Float16)v;
          } else {
            C[(size_t)(m0 + q) * N + n0] = v;
          }
        }
      }
    }
  }
}

// combine K-split partials: out = sum_kb part[kb] + bias (+ residual). N=512.
template <int HASR>
__global__ __launch_bounds__(256) void combine_kernel(
    const float* __restrict__ part, const float* __restrict__ bias,
    const float* Rres, float* __restrict__ Cout, size_t MN, int ks) {
  size_t gid = (size_t)blockIdx.x * 256 + threadIdx.x;
  int c = (int)(gid & 511);
  float v = 0.f;
  for (int kb = 0; kb < ks; kb++) v += part[kb * MN + gid];
  v += bias[c];
  if (HASR) v += Rres[gid];
  Cout[gid] = v;
}

// ---------------------------------------------------------------- weight split (fp32 -> f16 hi/lo planes)
// hi at o[g], lo at o[ps+g] (ps = plane stride; callers may concatenate rows)
__global__ __launch_bounds__(256) void splitw_kernel(const float* __restrict__ w,
                                                     _Float16* __restrict__ o,
                                                     int n, int ps) {
  int g = (blockIdx.x * 256 + threadIdx.x) << 2;
  if (g >= n) return;
  f32x4 f = *(const f32x4*)(w + g);
  f16x4 hv, lv;
#pragma unroll
  for (int q = 0; q < 4; ++q) {
    _Float16 h = (_Float16)f[q];
    hv[q] = h;
    lv[q] = (_Float16)(f[q] - (float)h);
  }
  *(f16x4*)(o + g) = hv;
  *(f16x4*)(o + ps + g) = lv;
}

// bias concat for fused QKV: o[0:512)=a, [512:1024)=b, [1024:1536)=c
__global__ void biascat_kernel(const float* __restrict__ a,
                               const float* __restrict__ b,
                               const float* __restrict__ c,
                               float* __restrict__ o) {
  int g = blockIdx.x * 256 + threadIdx.x;
  if (g < 512) o[g] = a[g];
  else if (g < 1024) o[g] = b[g - 512];
  else if (g < 1536) o[g] = c[g - 1024];
}

// ---------------------------------------------------------------- token conv + pos embed
__global__ void tokpe_kernel(const float* __restrict__ xe,
                             const float* __restrict__ w,
                             float* __restrict__ out, int S) {
  int gid = blockIdx.x * 256 + threadIdx.x;  // B*S*512
  int o = gid & 511;
  int bt = gid >> 9;
  int t = bt % S, b = bt / S;
  float acc = 0.f;
#pragma unroll
  for (int ww = 0; ww < 3; ww++) {
    int tt = t - 1 + ww;
    tt = (tt < 0) ? tt + S : (tt >= S ? tt - S : tt);
    const float* xr = xe + ((size_t)(b * S + tt)) * 7;
#pragma unroll
    for (int i = 0; i < 7; i++) acc += xr[i] * w[o * 21 + i * 3 + ww];
  }
  int i2 = o >> 1;
  float dv = expf((float)(2 * i2) * (-9.210340371976184f / 512.0f));
  float ang = (float)t * dv;
  acc += (o & 1) ? cosf(ang) : sinf(ang);
  out[gid] = acc;
}

// ---------------------------------------------------------------- conv weight pack (emit f16 hi/lo planes directly)
__global__ void packw_kernel(const float* __restrict__ dw,
                             _Float16* __restrict__ wp) {
  int gid = blockIdx.x * 256 + threadIdx.x;  // 512*1536
  int o = gid / 1536;
  int kk = gid - o * 1536;
  int ww = kk / 512;
  int c = kk - ww * 512;
  float v = dw[((size_t)o * 512 + c) * 3 + ww];
  _Float16 h = (_Float16)v;
  wp[gid] = h;
  wp[786432 + gid] = (_Float16)(v - (float)h);
}

// ---------------------------------------------------------------- M score
// quad-per-(b,h,t): 4 lanes split d=64 into 16 floats each (64B-contiguous per
// quad per instruction). b = blk&7 keeps batch->XCD affinity.
__global__ __launch_bounds__(256, 8) void mscore_kernel(
    const float* __restrict__ Q, const float* __restrict__ Kb,
    const int* __restrict__ idxb, float* __restrict__ Mout, int L, int U) {
  int i = blockIdx.x;        // grid = L blocks
  int b = i & 7;             // batch -> XCD
  int j = i >> 3;            // [0, L/8)
  int tid = threadIdx.x;
  int qd = tid >> 2;         // quad 0..63
  int q = tid & 3;           // lane in quad
  int h = qd & 7;            // head fastest: half-wave covers one K row fully
  int t = j * 8 + (qd >> 3);
  const float* qp = Q + ((size_t)(b * L + t)) * DMODEL + h * HD + q * 4;
  float4 qv0 = *(const float4*)(qp);
  float4 qv1 = *(const float4*)(qp + 16);
  float4 qv2 = *(const float4*)(qp + 32);
  float4 qv3 = *(const float4*)(qp + 48);
  const float* Kh = Kb + (size_t)b * L * DMODEL + h * HD + q * 4;
  const int* ip = idxb + t * U;
  float mx = -3.4e38f, sm = 0.f;
  int kr = ip[0];
  for (int jj = 0; jj < U; jj++) {
    const float* kp = Kh + (size_t)kr * DMODEL;
    float4 k0 = *(const float4*)(kp);
    float4 k1 = *(const float4*)(kp + 16);
    float4 k2 = *(const float4*)(kp + 32);
    float4 k3 = *(const float4*)(kp + 48);
    if (jj + 1 < U) kr = ip[jj + 1];
    float d = qv0.x * k0.x + qv0.y * k0.y + qv0.z * k0.z + qv0.w * k0.w +
              qv1.x * k1.x + qv1.y * k1.y + qv1.z * k1.z + qv1.w * k1.w +
              qv2.x * k2.x + qv2.y * k2.y + qv2.z * k2.z + qv2.w * k2.w +
              qv3.x * k3.x + qv3.y * k3.y + qv3.z * k3.z + qv3.w * k3.w;
    d += __shfl_xor(d, 1);
    d += __shfl_xor(d, 2);
    mx = fmaxf(mx, d);
    sm += d;
  }
  if (q == 0) Mout[(size_t)(b * 8 + h) * L + t] = mx - sm / (float)L;
}

// ---------------------------------------------------------------- top-k (per b,h), register-resident
__global__ __launch_bounds__(256) void topk_kernel(const float* __restrict__ Mv,
                                                   int* __restrict__ topb, int L,
                                                   int u) {
  __shared__ float wv_s[4];
  __shared__ int wi_s[4];
  __shared__ int best_s;
  int bh = blockIdx.x, tid = threadIdx.x;
  int lane = tid & 63, w = tid >> 6;
  int cnt = L >> 8;  // 8 / 4 / 2
  float lv[8];
  for (int i = 0; i < cnt; i++) lv[i] = Mv[(size_t)bh * L + i * 256 + tid];
  for (int r = 0; r < u; r++) {
    float bv = -3.4e38f;
    int bi = 0x7fffffff;
    for (int i = 0; i < cnt; i++) {
      if (lv[i] > bv) { bv = lv[i]; bi = i * 256 + tid; }
    }
    for (int s = 32; s > 0; s >>= 1) {
      float ov = __shfl_down(bv, s);
      int oi = __shfl_down(bi, s);
      if (ov > bv || (ov == bv && oi < bi)) { bv = ov; bi = oi; }
    }
    if (lane == 0) { wv_s[w] = bv; wi_s[w] = bi; }
    __syncthreads();
    if (tid == 0) {
      float fv = wv_s[0];
      int fi = wi_s[0];
      for (int q = 1; q < 4; q++) {
        if (wv_s[q] > fv || (wv_s[q] == fv && wi_s[q] < fi)) {
          fv = wv_s[q];
          fi = wi_s[q];
        }
      }
      best_s = fi;
      topb[bh * u + r] = fi;
    }
    __syncthreads();
    int win = best_s;
    if ((win & 255) == tid) lv[win >> 8] = -3.4e38f;
  }
}

// ---------------------------------------------------------------- gather selected q rows
__global__ void gatherq_kernel(const float* __restrict__ Q,
                               const int* __restrict__ topb,
                               float* __restrict__ qsel, int L, int u) {
  int i = blockIdx.x;  // (b*8+h)*u + r
  int bh = i / u;
  int b = bh >> 3, h = bh & 7;
  int t = topb[i];
  qsel[i * HD + threadIdx.x] =
      Q[((size_t)(b * L + t)) * DMODEL + h * HD + threadIdx.x];
}

// ---------------------------------------------------------------- mean of x rows per batch (partial)
__global__ __launch_bounds__(256) void xmean_kernel(const float* __restrict__ x,
                                                    float* __restrict__ psumx,
                                                    int L) {
  int i = blockIdx.x;  // 64: b*8+g
  int b = i >> 3, g = i & 7;
  int rows = L >> 3;
  int tid = threadIdx.x;
  const float* base = x + ((size_t)b * L + (size_t)g * rows) * DMODEL;
  float s0 = 0.f, s1 = 0.f;
  for (int t = 0; t < rows; t++) {
    s0 += base[(size_t)t * DMODEL + tid];
    s1 += base[(size_t)t * DMODEL + tid + 256];
  }
  psumx[i * DMODEL + tid] = s0;
  psumx[i * DMODEL + tid + 256] = s1;
}

// mv = xmean@Wv^T + bv ; mvWo = mv@Wo^T + bo
__global__ __launch_bounds__(256) void mvmake_kernel(
    const float* __restrict__ psumx, const float* __restrict__ Wv,
    const float* __restrict__ bv, const float* __restrict__ Wo,
    const float* __restrict__ bo, float* __restrict__ mvg,
    float* __restrict__ mvWog, int L) {
  __shared__ float xm[512];
  __shared__ float mvs[512];
  int b = blockIdx.x, tid = threadIdx.x;
  float inv = 1.0f / (float)L;
  for (int nn = 0; nn < 2; nn++) {
    int c = tid + nn * 256;
    float s = 0.f;
    for (int g = 0; g < 8; g++) s += psumx[(b * 8 + g) * DMODEL + c];
    xm[c] = s * inv;
  }
  __syncthreads();
  for (int nn = 0; nn < 2; nn++) {
    int n = tid + nn * 256;
    const float* wr = Wv + (size_t)n * 512;
    float s = bv[n];
    for (int k = 0; k < 512; k += 4) {
      float4 w4 = *(const float4*)(wr + k);
      s += xm[k] * w4.x + xm[k + 1] * w4.y + xm[k + 2] * w4.z + xm[k + 3] * w4.w;
    }
    mvs[n] = s;
    mvg[b * DMODEL + n] = s;
  }
  __syncthreads();
  for (int nn = 0; nn < 2; nn++) {
    int n = tid + nn * 256;
    const float* wr = Wo + (size_t)n * 512;
    float s = bo[n];
    for (int k = 0; k < 512; k += 4) {
      float4 w4 = *(const float4*)(wr + k);
      s += mvs[k] * w4.x + mvs[k + 1] * w4.y + mvs[k + 2] * w4.z +
           mvs[k + 3] * w4.w;
    }
    mvWog[b * DMODEL + n] = s;
  }
}

// x1 = x + mvWo[b] (broadcast)
__global__ void x1bcast_kernel(const float* __restrict__ x,
                               const float* __restrict__ mvWog,
                               float* __restrict__ x1, int L) {
  int gid = blockIdx.x * 256 + threadIdx.x;  // BL*512
  int c = gid & 511;
  int r = gid >> 9;
  int b = r / L;
  x1[gid] = x[gid] + mvWog[b * DMODEL + c];
}

// ---------------------------------------------------------------- chunked flash attention for selected rows
// nchunk = L/64 -> one 64-key tile per block; grid 64*nchunk fills the machine
// (LDS 30 KB -> 5 blocks/CU = 20 waves/CU).
__global__ __launch_bounds__(256) void attnflash_kernel(
    const float* __restrict__ qsel, const float* __restrict__ Kb,
    const float* __restrict__ Vb, float* __restrict__ pm,
    float* __restrict__ pl, float* __restrict__ pO, int L, int u, int nchunk) {
  __shared__ float qs[24][64];
  __shared__ float Kt[64][68];   // transposed K tile: Kt[d][j]
  __shared__ float Ps[24][68];   // P row per query (wave-local rows)
  int blk = blockIdx.x;          // bh*nchunk + c
  int bh = blk / nchunk;
  int c = blk - bh * nchunk;
  int b = bh >> 3, h = bh & 7;
  int cs = L / nchunk;
  int tid = threadIdx.x;
  int lane = tid & 63;
  int w = tid >> 6;
  for (int i = tid; i < u * 64; i += 256)
    qs[i >> 6][i & 63] = qsel[(size_t)bh * u * 64 + i];
  float m[6], l[6], O[6];
#pragma unroll
  for (int k = 0; k < 6; k++) { m[k] = -3.4e38f; l[k] = 0.f; O[k] = 0.f; }
  const float* Kbase = Kb + (size_t)b * L * DMODEL + h * HD;
  const float* Vbase = Vb + (size_t)b * L * DMODEL + h * HD;
  const int jrow = tid & 63;        // staging row
  const int dch = (tid >> 6) << 4;  // staging d-chunk base (0,16,32,48)
  for (int j0 = c * cs; j0 < (c + 1) * cs; j0 += 64) {
    __syncthreads();  // protect Kt (and qs on first iter)
    const float* kr = Kbase + (size_t)(j0 + jrow) * DMODEL + dch;
    float4 k0 = *(const float4*)(kr);
    float4 k1 = *(const float4*)(kr + 4);
    float4 k2 = *(const float4*)(kr + 8);
    float4 k3 = *(const float4*)(kr + 12);
#pragma unroll
    for (int q = 0; q < 4; q++) {
      Kt[dch + q][jrow] = ((float*)&k0)[q];
      Kt[dch + 4 + q][jrow] = ((float*)&k1)[q];
      Kt[dch + 8 + q][jrow] = ((float*)&k2)[q];
      Kt[dch + 12 + q][jrow] = ((float*)&k3)[q];
    }
    __syncthreads();
#pragma unroll
    for (int k = 0; k < 6; k++) {
      int qi = 4 * k + w;
      if (qi >= u) break;
      float s = 0.f;
#pragma unroll
      for (int d = 0; d < 64; d++) s += qs[qi][d] * Kt[d][lane];
      s *= 0.125f;
      float mx = s;
#pragma unroll
      for (int off = 32; off > 0; off >>= 1)
        mx = fmaxf(mx, __shfl_down(mx, off));
      mx = __shfl(mx, 0);
      float mnew = fmaxf(m[k], mx);
      float p = expf(s - mnew);
      float ps = p;
#pragma unroll
      for (int off = 32; off > 0; off >>= 1) ps += __shfl_down(ps, off);
      ps = __shfl(ps, 0);
      float alpha = expf(m[k] - mnew);
      l[k] = l[k] * alpha + ps;
      m[k] = mnew;
      O[k] *= alpha;
      Ps[qi][lane] = p;
    }
    for (int j = 0; j < 64; j += 4) {
      float v0 = Vbase[(size_t)(j0 + j) * DMODEL + lane];
      float v1 = Vbase[(size_t)(j0 + j + 1) * DMODEL + lane];
      float v2 = Vbase[(size_t)(j0 + j + 2) * DMODEL + lane];
      float v3 = Vbase[(size_t)(j0 + j + 3) * DMODEL + lane];
#pragma unroll
      for (int k = 0; k < 6; k++) {
        int qi = 4 * k + w;
        if (qi >= u) break;
        O[k] += Ps[qi][j] * v0 + Ps[qi][j + 1] * v1 + Ps[qi][j + 2] * v2 +
                Ps[qi][j + 3] * v3;
      }
    }
  }
#pragma unroll
  for (int k = 0; k < 6; k++) {
    int qi = 4 * k + w;
    if (qi < u) {
      int p = (bh * nchunk + c) * u + qi;
      if (lane == 0) { pm[p] = m[k]; pl[p] = l[k]; }
      pO[(size_t)p * 64 + lane] = O[k];
    }
  }
}

// combine chunk partials + scatter: x1[row] += (O/l - mv) @ Wo[:, h-block]^T
__global__ __launch_bounds__(256) void deltaWo_kernel(
    const float* __restrict__ pm, const float* __restrict__ pl,
    const float* __restrict__ pO, const float* __restrict__ mvg,
    const int* __restrict__ topb, const float* __restrict__ Wo, float* x1,
    int L, int u, int nchunk) {
  __shared__ float ds[64];
  int sel = blockIdx.x;  // (b*8+h)*u + qi
  int bh = sel / u;
  int qi = sel - bh * u;
  int b = bh >> 3, h = bh & 7;
  int t = topb[sel];
  int tid = threadIdx.x;
  if (tid < 64) {
    float mstar = -3.4e38f;
    for (int c = 0; c < nchunk; c++)
      mstar = fmaxf(mstar, pm[(bh * nchunk + c) * u + qi]);
    float lstar = 0.f, O = 0.f;
    for (int c = 0; c < nchunk; c++) {
      int p = (bh * nchunk + c) * u + qi;
      float wgt = expf(pm[p] - mstar);
      lstar += wgt * pl[p];
      O += wgt * pO[(size_t)p * 64 + tid];
    }
    ds[tid] = O / lstar - mvg[b * DMODEL + h * HD + tid];
  }
  __syncthreads();
  float* row = x1 + ((size_t)(b * L + t)) * DMODEL;
  for (int nn = 0; nn < 2; nn++) {
    int n = tid + nn * 256;
    const float* wr = Wo + (size_t)n * 512 + h * HD;
    float a = 0.f;
#pragma unroll
    for (int k = 0; k < 64; k += 4) {
      float4 w4 = *(const float4*)(wr + k);
      a += ds[k] * w4.x + ds[k + 1] * w4.y + ds[k + 2] * w4.z + ds[k + 3] * w4.w;
    }
    atomicAdd(row + n, a);
  }
}

// ---------------------------------------------------------------- layernorm (512 cols), wave-per-row
__global__ __launch_bounds__(256) void ln_kernel(const float* __restrict__ X,
                                                 const float* __restrict__ g,
                                                 const float* __restrict__ bta,
                                                 float* __restrict__ Y) {
  int row = blockIdx.x * 4 + (threadIdx.x >> 6);
  int lane = threadIdx.x & 63;
  size_t base = (size_t)row * DMODEL + lane * 8;
  float4 a = *(const float4*)(X + base);
  float4 b = *(const float4*)(X + base + 4);
  float s = a.x + a.y + a.z + a.w + b.x + b.y + b.z + b.w;
#pragma unroll
  for (int off = 32; off > 0; off >>= 1) s += __shfl_xor(s, off);
  float mean = s * (1.0f / 512.0f);
  float d[8];
  d[0] = a.x - mean; d[1] = a.y - mean; d[2] = a.z - mean; d[3] = a.w - mean;
  d[4] = b.x - mean; d[5] = b.y - mean; d[6] = b.z - mean; d[7] = b.w - mean;
  float q = 0.f;
#pragma unroll
  for (int i = 0; i < 8; ++i) q += d[i] * d[i];
#pragma unroll
  for (int off = 32; off > 0; off >>= 1) q += __shfl_xor(q, off);
  float inv = 1.0f / sqrtf(q * (1.0f / 512.0f) + 1e-5f);
  int col = lane * 8;
  float4 g0 = *(const float4*)(g + col);
  float4 g1 = *(const float4*)(g + col + 4);
  float4 t0 = *(const float4*)(bta + col);
  float4 t1 = *(const float4*)(bta + col + 4);
  float4 y0, y1;
  y0.x = d[0] * inv * g0.x + t0.x; y0.y = d[1] * inv * g0.y + t0.y;
  y0.z = d[2] * inv * g0.z + t0.z; y0.w = d[3] * inv * g0.w + t0.w;
  y1.x = d[4] * inv * g1.x + t1.x; y1.y = d[5] * inv * g1.y + t1.y;
  y1.z = d[6] * inv * g1.z + t1.z; y1.w = d[7] * inv * g1.w + t1.w;
  *(float4*)(Y + base) = y0;
  *(float4*)(Y + base + 4) = y1;
}

// ---------------------------------------------------------------- BN stats + pool
__global__ __launch_bounds__(256) void bnpart_kernel(const float* __restrict__ z,
                                                     float* __restrict__ psum,
                                                     float* __restrict__ psq,
                                                     int rowsPer) {
  int blk = blockIdx.x, tid = threadIdx.x;
  size_t r0 = (size_t)blk * rowsPer;
  float s0 = 0, q0 = 0, s1 = 0, q1 = 0;
  for (int r = 0; r < rowsPer; r++) {
    const float* zp = z + (r0 + r) * DMODEL;
    float a = zp[tid];
    s0 += a; q0 += a * a;
    float c = zp[tid + 256];
    s1 += c; q1 += c * c;
  }
  psum[blk * DMODEL + tid] = s0;
  psum[blk * DMODEL + tid + 256] = s1;
  psq[blk * DMODEL + tid] = q0;
  psq[blk * DMODEL + tid + 256] = q1;
}

__global__ void bnfin_kernel(const float* __restrict__ psum,
                             const float* __restrict__ psq, float* __restrict__ mu,
                             float* __restrict__ var, int nb, int Rtot) {
  int c = blockIdx.x * 256 + threadIdx.x;
  float s = 0, q = 0;
  for (int b = 0; b < nb; b++) {
    s += psum[b * DMODEL + c];
    q += psq[b * DMODEL + c];
  }
  float m = s / (float)Rtot;
  mu[c] = m;
  var[c] = fmaxf(q / (float)Rtot - m * m, 0.f);
}

__global__ void bnpool_kernel(const float* __restrict__ z,
                              const float* __restrict__ mu,
                              const float* __restrict__ var,
                              const float* __restrict__ g,
                              const float* __restrict__ bta,
                              float* __restrict__ out, int L) {
  int gid = blockIdx.x * 256 + threadIdx.x;  // B*(L/2)*512
  int c = gid & 511;
  int bt = gid >> 9;
  int L2 = L >> 1;
  int t2 = bt % L2, b = bt / L2;
  float m = mu[c];
  float inv = 1.0f / sqrtf(var[c] + 1e-5f);
  float gg = g[c], bb = bta[c];
  float best = -3.4e38f;
#pragma unroll
  for (int ww = 0; ww < 3; ww++) {
    int t = 2 * t2 - 1 + ww;
    if (t < 0 || t >= L) continue;
    float yv = (z[((size_t)(b * L + t)) * DMODEL + c] - m) * inv * gg + bb;
    yv = (yv > 0.f) ? yv : expm1f(yv);
    best = fmaxf(best, yv);
  }
  out[gid] = best;
}

// ---------------------------------------------------------------- final projection (512 -> 7)
__global__ __launch_bounds__(64) void end_kernel(const float* __restrict__ xn,
                                                 const float* __restrict__ ew,
                                                 const float* __restrict__ eb,
                                                 float* __restrict__ out) {
  __shared__ float xs[512];
  __shared__ float red[64];
  int row = blockIdx.x, tid = threadIdx.x;
#pragma unroll
  for (int i = 0; i < 8; i++) xs[tid + 64 * i] = xn[(size_t)row * DMODEL + tid + 64 * i];
  __syncthreads();
  for (int c = 0; c < 7; c++) {
    float p = 0.f;
    for (int d = tid; d < 512; d += 64) p += xs[d] * ew[c * DMODEL + d];
    red[tid] = p;
    __syncthreads();
    for (int s = 32; s > 0; s >>= 1) {
      if (tid < s) red[tid] += red[tid + s];
      __syncthreads();
    }
    if (tid == 0) out[row * 7 + c] = red[0] + eb[c];
    __syncthreads();
  }
}

// ---------------------------------------------------------------- host
extern "C" void kernel_launch(void* const* d_in, const int* in_sizes, int n_in,
                              void* d_out, int out_size, void* d_ws,
                              size_t ws_size, hipStream_t stream) {
  (void)in_sizes; (void)n_in; (void)out_size;
  const float* x_enc = (const float*)d_in[0];
  const float* tok_w = (const float*)d_in[1];
  const float* Wq = (const float*)d_in[2];
  const float* bq = (const float*)d_in[3];
  const float* Wk = (const float*)d_in[4];
  const float* bk = (const float*)d_in[5];
  const float* Wv = (const float*)d_in[6];
  const float* bv = (const float*)d_in[7];
  const float* Wo = (const float*)d_in[8];
  const float* bo = (const float*)d_in[9];
  const float* w1 = (const float*)d_in[10];
  const float* b1 = (const float*)d_in[11];
  const float* w2 = (const float*)d_in[12];
  const float* b2 = (const float*)d_in[13];
  const float* g1 = (const float*)d_in[14];
  const float* be1 = (const float*)d_in[15];
  const float* g2 = (const float*)d_in[16];
  const float* be2 = (const float*)d_in[17];
  const float* dw = (const float*)d_in[18];
  const float* db = (const float*)d_in[19];
  const float* bng = (const float*)d_in[20];
  const float* bnb = (const float*)d_in[21];
  const float* lnfg = (const float*)d_in[22];
  const float* lnfb = (const float*)d_in[23];
  const float* endw = (const float*)d_in[24];
  const float* endb = (const float*)d_in[25];
  float* out = (float*)d_out;
  char* ws = (char*)d_ws;

  const int NCHMAX = 32;  // attention key chunks (layer 0: L/64 = 32)

  // ---- arena ----
  size_t o = 0;
  float* buf0 = (float*)(ws + o); o += (size_t)16384 * 512 * 4;  // x / CH(4096x2048)
  float* qbuf = (float*)(ws + o); o += (size_t)16384 * 512 * 4;  // Q / xa
  float* kbuf = (float*)(ws + o); o += (size_t)16384 * 512 * 4;  // K / x1=z
  float* wpack = (float*)(ws + o); o += (size_t)512 * 1536 * 4;  // conv W (f16 hi/lo planes)
  float* Mb    = (float*)(ws + o); o += (size_t)64 * 2048 * 4;
  int*   idxb  = (int*)(ws + o);   o += (size_t)2048 * 24 * 4;
  int*   topb  = (int*)(ws + o);   o += 8192;
  float* qsel  = (float*)(ws + o); o += (size_t)64 * 24 * 64 * 4;
  float* mvg   = (float*)(ws + o); o += (size_t)8 * 512 * 4;
  float* mvWog = (float*)(ws + o); o += (size_t)8 * 512 * 4;
  float* psumx = (float*)(ws + o); o += (size_t)64 * 512 * 4;
  float* psum  = (float*)(ws + o); o += (size_t)128 * 512 * 4;
  float* psq   = (float*)(ws + o); o += (size_t)128 * 512 * 4;
  float* muv   = (float*)(ws + o); o += 2048;
  float* varv  = (float*)(ws + o); o += 2048;
  float* biasc = (float*)(ws + o); o += 8192;   // fused QKV bias (1536 used)
  float* pmb   = (float*)(ws + o); o += (size_t)64 * NCHMAX * 24 * 4;
  float* plb   = (float*)(ws + o); o += (size_t)64 * NCHMAX * 24 * 4;
  float* pOb   = (float*)(ws + o); o += (size_t)64 * NCHMAX * 24 * 64 * 4;
  // f16 hi/lo split weight buffers (2B * 2 planes = 4B per element)
  _Float16* w1s = (_Float16*)(ws + o); o += (size_t)2048 * 512 * 4;   // 4 MB (also QKV 3MB scratch)
  _Float16* w2s = (_Float16*)(ws + o); o += (size_t)512 * 2048 * 4;   // 4 MB
  float* partb = (float*)(ws + o); o += (size_t)4 * 4096 * 2048;  // 33.6 MB: V buffer / K-split partials
  const bool uks = (ws_size >= o);  // K-split / V-buffer path allowed
  float* vbuf = partb;              // V lives here until attnflash consumes it
  // full-M FFN intermediate; f16 plane (64 MB used of 128 MB)
  float* chbuf = (float*)(ws + o); o += (size_t)16384 * 2048 * 4;
  const bool ubig = (ws_size >= o);
  _Float16* chbuf16 = (_Float16*)chbuf;

  const int B = 8;
  const int S = 2048;
  tokpe_kernel<<<B * S * DMODEL / 256, 256, 0, stream>>>(x_enc, tok_w, buf0, S);

  int L = S;
  const int Uarr[3] = {24, 21, 21};  // 3*ceil(ln(L)) for 2048,1024,512
  for (int l = 0; l < 3; l++) {
    int U = Uarr[l];
    int u = Uarr[l];
    int BL = B * L;
    int nty = BL >> 7;   // 128-row tiles: 128 / 64 / 32
    size_t MN = (size_t)BL * 512;
    int nch = L >> 6;    // one 64-key tile per block: 32 / 16 / 8
    idx_kernel<<<(L * U + 255) / 256, 256, 0, stream>>>(idxb, L * U, l, L - 1);

    // ---- fused QKV: one N=1536 GEMM. Q/K full PREC=3 (bit-identical ->
    // top-k safe); V column group runs single-product at runtime. ----
    splitw_kernel<<<256, 256, 0, stream>>>(Wq + (size_t)l * 262144, w1s,
                                           262144, 786432);
    splitw_kernel<<<256, 256, 0, stream>>>(Wk + (size_t)l * 262144,
                                           w1s + 262144, 262144, 786432);
    splitw_kernel<<<256, 256, 0, stream>>>(Wv + (size_t)l * 262144,
                                           w1s + 524288, 262144, 786432);
    biascat_kernel<<<6, 256, 0, stream>>>(bq + l * 512, bk + l * 512,
                                          bv + l * 512, biasc);
    gemm128<0, 0, 0, 0, 3, 1, 0, 0><<<nty * 12, 256, 0, stream>>>(
        buf0, w1s, biasc, nullptr, qbuf, kbuf, vbuf, 1536, 512, 0, 12, nty,
        512, 1);

    mscore_kernel<<<L, 256, 0, stream>>>(qbuf, kbuf, idxb, Mb, L, U);
    topk_kernel<<<64, 256, 0, stream>>>(Mb, topb, L, u);
    gatherq_kernel<<<64 * u, 64, 0, stream>>>(qbuf, topb, qsel, L, u);
    xmean_kernel<<<64, 256, 0, stream>>>(buf0, psumx, L);
    mvmake_kernel<<<8, 256, 0, stream>>>(psumx, Wv + (size_t)l * 262144,
                                         bv + l * 512, Wo + (size_t)l * 262144,
                                         bo + l * 512, mvg, mvWog, L);
    attnflash_kernel<<<64 * nch, 256, 0, stream>>>(qsel, kbuf, vbuf, pmb, plb,
                                                   pOb, L, u, nch);
    // x1 = x + mvWo (into kbuf) ; += sparse delta@Wo
    x1bcast_kernel<<<(unsigned)(MN / 256), 256, 0, stream>>>(buf0, mvWog, kbuf, L);
    deltaWo_kernel<<<64 * u, 256, 0, stream>>>(pmb, plb, pOb, mvg, topb,
                                               Wo + (size_t)l * 262144, kbuf, L,
                                               u, nch);
    // xa = LN1(x1) -> qbuf
    ln_kernel<<<BL / 4, 256, 0, stream>>>(kbuf, g1 + l * 512, be1 + l * 512, qbuf);
    // FFN (PREC=1)
    splitw_kernel<<<1024, 256, 0, stream>>>(w1 + (size_t)l * 1048576, w1s,
                                            1048576, 1048576);
    splitw_kernel<<<1024, 256, 0, stream>>>(w2 + (size_t)l * 1048576, w2s,
                                            1048576, 1048576);
    if (ubig) {
      // full-M FFN1 -> chbuf as f16 (OF16). Numerically identical to fp32
      // chbuf + PREC=1 staging (which rounds A to f16-hi anyway).
      gemm128<1, 0, 0, 0, 1, 0, 0, 1><<<16 * nty, 256, 0, stream>>>(
          qbuf, w1s, b1 + l * 2048, nullptr, chbuf, nullptr, nullptr, 2048,
          512, 0, 16, nty, 512, 1);
      if (4 * nty >= 256) {
        // full-M FFN2 direct, f16 A-read (AF16), residual+bias fused
        gemm128<0, 1, 0, 0, 1, 0, 1, 0><<<4 * nty, 256, 0, stream>>>(
            chbuf16, w2s, b2 + l * 512, qbuf, kbuf, nullptr, nullptr, 512,
            2048, 0, 4, nty, 2048, 1);
      } else {
        // small grid (L2): K-split 4 into partb (V consumed already)
        gemm128<0, 0, 0, 1, 1, 0, 1, 0><<<4 * nty * 4, 256, 0, stream>>>(
            chbuf16, w2s, nullptr, nullptr, partb, nullptr, nullptr, 512, 2048,
            0, 4, nty, 512, 4);
        combine_kernel<1><<<(unsigned)(MN / 256), 256, 0, stream>>>(
            partb, b2 + l * 512, qbuf, kbuf, MN, 4);
      }
    } else {
      // fallback: 4096-row chunks; CH = buf0 fp32 (x dead). Residual = qbuf.
      for (int r0 = 0; r0 < BL; r0 += 4096) {
        gemm128<1, 0, 0, 0, 1, 0, 0, 0><<<16 * 32, 256, 0, stream>>>(
            qbuf + (size_t)r0 * 512, w1s, b1 + l * 2048, nullptr, buf0, nullptr,
            nullptr, 2048, 512, 0, 16, 32, 512, 1);
        if (uks) {
          gemm128<0, 0, 0, 1, 1, 0, 0, 0><<<4 * 32 * 4, 256, 0, stream>>>(
              buf0, w2s, nullptr, nullptr, partb, nullptr, nullptr, 512, 2048,
              0, 4, 32, 512, 4);
          combine_kernel<1><<<4096 * 512 / 256, 256, 0, stream>>>(
              partb, b2 + l * 512, qbuf + (size_t)r0 * 512,
              kbuf + (size_t)r0 * 512, (size_t)4096 * 512, 4);
        } else {
          gemm128<0, 1, 0, 0, 1, 0, 0, 0><<<4 * 32, 256, 0, stream>>>(
              buf0, w2s, b2 + l * 512, qbuf + (size_t)r0 * 512,
              kbuf + (size_t)r0 * 512, nullptr, nullptr, 512, 2048, 0, 4, 32,
              2048, 1);
        }
      }
    }
    // x = LN2(z) -> buf0
    ln_kernel<<<BL / 4, 256, 0, stream>>>(kbuf, g2 + l * 512, be2 + l * 512, buf0);

    if (l < 2) {
      packw_kernel<<<512 * 1536 / 256, 256, 0, stream>>>(
          dw + (size_t)l * 512 * 512 * 3, (_Float16*)wpack);
      int gqc = 4 * nty;
      int ksc = (gqc >= 512 || !uks) ? 1 : 2;  // conv K=1536 (PREC=1)
      if (ksc == 1) {
        gemm128<0, 0, 1, 0, 1, 0, 0, 0><<<gqc, 256, 0, stream>>>(
            buf0, wpack, db + l * 512, nullptr, kbuf, nullptr, nullptr, 512,
            1536, L - 1, 4, nty, 1536, 1);
      } else {
        gemm128<0, 0, 1, 1, 1, 0, 0, 0><<<gqc * 2, 256, 0, stream>>>(
            buf0, wpack, nullptr, nullptr, partb, nullptr, nullptr, 512, 1536,
            L - 1, 4, nty, 768, 2);
        combine_kernel<0><<<(unsigned)(MN / 256), 256, 0, stream>>>(
            partb, db + l * 512, nullptr, kbuf, MN, 2);
      }
      int nb = BL / 128;
      bnpart_kernel<<<nb, 256, 0, stream>>>(kbuf, psum, psq, 128);
      bnfin_kernel<<<2, 256, 0, stream>>>(psum, psq, muv, varv, nb, BL);
      bnpool_kernel<<<(BL / 2) * 512 / 256, 256, 0, stream>>>(
          kbuf, muv, varv, bng + l * 512, bnb + l * 512, buf0, L);
      L >>= 1;
    }
  }
  int BL = B * L;  // 4096
  ln_kernel<<<BL / 4, 256, 0, stream>>>(buf0, lnfg, lnfb, qbuf);
  end_kernel<<<BL, 64, 0, stream>>>(qbuf, endw, endb, out);
}

// Round 13
// 1662.683 us; speedup vs baseline: 1.0303x; 1.0303x over previous
//
#include <hip/hip_runtime.h>
#include <cstdint>
#include <cstddef>

#define DMODEL 512
#define NHEAD 8
#define HD 64

typedef float f32x4 __attribute__((ext_vector_type(4)));
typedef _Float16 f16x8 __attribute__((ext_vector_type(8)));
typedef _Float16 f16x4 __attribute__((ext_vector_type(4)));

// ---------------------------------------------------------------- threefry
__device__ __forceinline__ uint32_t rotl32(uint32_t x, int r) {
  return (x << r) | (x >> (32 - r));
}

__device__ __forceinline__ void tf_block(uint32_t k0, uint32_t k1,
                                         uint32_t& x0, uint32_t& x1) {
  uint32_t ks0 = k0, ks1 = k1, ks2 = k0 ^ k1 ^ 0x1BD11BDAu;
  x0 += ks0; x1 += ks1;
  x0 += x1; x1 = rotl32(x1, 13); x1 ^= x0;
  x0 += x1; x1 = rotl32(x1, 15); x1 ^= x0;
  x0 += x1; x1 = rotl32(x1, 26); x1 ^= x0;
  x0 += x1; x1 = rotl32(x1, 6);  x1 ^= x0;
  x0 += ks1; x1 += ks2 + 1u;
  x0 += x1; x1 = rotl32(x1, 17); x1 ^= x0;
  x0 += x1; x1 = rotl32(x1, 29); x1 ^= x0;
  x0 += x1; x1 = rotl32(x1, 16); x1 ^= x0;
  x0 += x1; x1 = rotl32(x1, 24); x1 ^= x0;
  x0 += ks2; x1 += ks0 + 2u;
  x0 += x1; x1 = rotl32(x1, 13); x1 ^= x0;
  x0 += x1; x1 = rotl32(x1, 15); x1 ^= x0;
  x0 += x1; x1 = rotl32(x1, 26); x1 ^= x0;
  x0 += x1; x1 = rotl32(x1, 6);  x1 ^= x0;
  x0 += ks0; x1 += ks1 + 3u;
  x0 += x1; x1 = rotl32(x1, 17); x1 ^= x0;
  x0 += x1; x1 = rotl32(x1, 29); x1 ^= x0;
  x0 += x1; x1 = rotl32(x1, 16); x1 ^= x0;
  x0 += x1; x1 = rotl32(x1, 24); x1 ^= x0;
  x0 += ks1; x1 += ks2 + 4u;
  x0 += x1; x1 = rotl32(x1, 13); x1 ^= x0;
  x0 += x1; x1 = rotl32(x1, 15); x1 ^= x0;
  x0 += x1; x1 = rotl32(x1, 26); x1 ^= x0;
  x0 += x1; x1 = rotl32(x1, 6);  x1 ^= x0;
  x0 += ks2; x1 += ks0 + 5u;
}

__global__ void idx_kernel(int* __restrict__ idxb, int n, int layer, int mask) {
  int e = blockIdx.x * 256 + threadIdx.x;
  if (e >= n) return;
  uint32_t f0 = 0u, f1 = (uint32_t)layer;
  tf_block(0u, 42u, f0, f1);
  uint32_t s0 = 0u, s1 = 1u;
  tf_block(f0, f1, s0, s1);
  uint32_t x0 = 0u, x1 = (uint32_t)e;
  tf_block(s0, s1, x0, x1);
  uint32_t bits = x0 ^ x1;
  idxb[e] = (int)(bits & (uint32_t)mask);
}

// ---------------------------------------------------------------- GEMM 128x128 MFMA (fp16 split emulation of fp32)
// PREC=3: acc += Ah*Wh + Ah*Wl + Al*Wh (rel err ~2^-23; bit-identical to
//         earlier rounds -> Q/K and top-k unchanged).
// PREC=1: acc += Ah*Wh only (rel err ~2^-11 ~ 1e-3) -- used for FFN/conv/V
//         paths that feed continuous, layernorm-renormalized outputs.
// FUSE3: N=1536 fused QKV; C-write selects {C,C2,C3} by column group (each
//        512-wide, ldc=512); bias is the concatenated biasc[1536].
// PART: block kb writes raw fp32 partial over K-slice into Cpart.
// CONV: logical A[r][k] = x[bbase + ((t-1+w)&Lmask)][k&511], w=k>>9 (K=1536).
__device__ __forceinline__ float gelu_f(float v) {
  return 0.5f * v * (1.0f + erff(v * 0.7071067811865476f));
}

template <int ACT, int HASR, int CONV, int PART, int PREC, int FUSE3>
__global__ __launch_bounds__(256, 2) void gemm128(
    const float* __restrict__ A, const void* __restrict__ Wsp,
    const float* __restrict__ bias, const float* Rres, float* C, float* C2,
    float* C3, int N, int K, int Lmask, int ntx, int nty, int kloop, int ks) {
  // planes: 0=Ah 1=Al 2=Wh 3=Wl ; [row][k], k-slot (8 elems = 16B) XOR-swizzled
  __shared__ __align__(16) _Float16 sm[4][128][32];
  const _Float16* Wh = (const _Float16*)Wsp;
  const _Float16* Wl = Wh + (size_t)N * K;
  const int tid = threadIdx.x;
  int blk = blockIdx.x;
  const int tiles = ntx * nty;
  int kb = 0;
  if (PART) { kb = blk / tiles; blk -= kb * tiles; }
  const int koff = kb * kloop;
  const int xcd = blk & 7;
  const int j = blk >> 3;
  const int jr = j / ntx;
  const int row_t = xcd * (nty >> 3) + jr;
  const int col_t = j - jr * ntx;
  const int row0 = row_t * 128, col0 = col_t * 128;

  const int r4 = tid >> 2;  // 0..63
  const int ss = tid & 3;   // k-slot (8 fp32 / 8 halves)

  const float* Ap0 = A + (size_t)(row0 + r4) * K + koff + ss * 8;
  const float* Ap1 = A + (size_t)(row0 + 64 + r4) * K + koff + ss * 8;
  const _Float16* Wh0 = Wh + (size_t)(col0 + r4) * K + koff + ss * 8;
  const _Float16* Wh1 = Wh + (size_t)(col0 + 64 + r4) * K + koff + ss * 8;
  const _Float16* Wl0 = Wl + (size_t)(col0 + r4) * K + koff + ss * 8;
  const _Float16* Wl1 = Wl + (size_t)(col0 + 64 + r4) * K + koff + ss * 8;
  int tcv0 = 0, bb0 = 0, tcv1 = 0, bb1 = 0;
  if (CONV) {
    int a0 = row0 + r4, a1 = row0 + 64 + r4;
    tcv0 = a0 & Lmask; bb0 = a0 & ~Lmask;
    tcv1 = a1 & Lmask; bb1 = a1 & ~Lmask;
  }

  // wave -> 64x64 sub-tile; 4x4 frags of 16x16, K=32 per MFMA
  const int lane = tid & 63;
  const int wv = tid >> 6;
  const int wr = (wv >> 1) << 6;
  const int wc = (wv & 1) << 6;
  const int fr = lane & 15;  // frag row (A) / col (B)
  const int fs = lane >> 4;  // frag k-slot

  f32x4 acc[4][4];
  {
    f32x4 z = {0.f, 0.f, 0.f, 0.f};
#pragma unroll
    for (int r = 0; r < 4; ++r)
#pragma unroll
      for (int c = 0; c < 4; ++c) acc[r][c] = z;
  }

  f32x4 ra[4], rwh[2], rwl[2];

  auto gload = [&](int k0) {
    const float *a0p, *a1p;
    if (CONV) {
      int kabs = koff + k0 + ss * 8;
      int w = kabs >> 9, cq = kabs & 511;
      a0p = A + (size_t)(bb0 | ((tcv0 - 1 + w) & Lmask)) * 512 + cq;
      a1p = A + (size_t)(bb1 | ((tcv1 - 1 + w) & Lmask)) * 512 + cq;
    } else {
      a0p = Ap0 + k0;
      a1p = Ap1 + k0;
    }
    ra[0] = *(const f32x4*)(a0p);
    ra[1] = *(const f32x4*)(a0p + 4);
    ra[2] = *(const f32x4*)(a1p);
    ra[3] = *(const f32x4*)(a1p + 4);
    rwh[0] = *(const f32x4*)(Wh0 + k0);
    rwh[1] = *(const f32x4*)(Wh1 + k0);
    if (PREC == 3) {
      rwl[0] = *(const f32x4*)(Wl0 + k0);
      rwl[1] = *(const f32x4*)(Wl1 + k0);
    }
  };

  const int T = kloop >> 5;  // BK = 32
  gload(0);

  for (int it = 0; it < T; ++it) {
    // stage regs -> LDS (A: fp32 -> f16 hi(/lo) split; W: pre-split copy)
#pragma unroll
    for (int p = 0; p < 2; ++p) {
      const int row = (p << 6) + r4;
      const int sl = (ss ^ ((row >> 1) & 3)) << 3;  // swizzled slot base
      float tmp[8];
      *(f32x4*)(tmp) = ra[2 * p];
      *(f32x4*)(tmp + 4) = ra[2 * p + 1];
      _Float16 hv[8], lv[8];
#pragma unroll
      for (int q = 0; q < 8; ++q) {
        _Float16 h = (_Float16)tmp[q];
        hv[q] = h;
        if (PREC == 3) lv[q] = (_Float16)(tmp[q] - (float)h);
      }
      *(f16x8*)&sm[0][row][sl] = *(f16x8*)hv;
      if (PREC == 3) *(f16x8*)&sm[1][row][sl] = *(f16x8*)lv;
      *(f32x4*)&sm[2][row][sl] = rwh[p];
      if (PREC == 3) *(f32x4*)&sm[3][row][sl] = rwl[p];
    }
    __syncthreads();
    if (it + 1 < T) gload((it + 1) << 5);  // prefetch overlaps MFMA below
    // fragments
    f16x8 wfh[4], wfl[4], afh[4], afl[4];
#pragma unroll
    for (int c = 0; c < 4; ++c) {
      const int row = wc + (c << 4) + fr;
      const int sl = (fs ^ ((row >> 1) & 3)) << 3;
      wfh[c] = *(const f16x8*)&sm[2][row][sl];
      if (PREC == 3) wfl[c] = *(const f16x8*)&sm[3][row][sl];
    }
#pragma unroll
    for (int r = 0; r < 4; ++r) {
      const int row = wr + (r << 4) + fr;
      const int sl = (fs ^ ((row >> 1) & 3)) << 3;
      afh[r] = *(const f16x8*)&sm[0][row][sl];
      if (PREC == 3) afl[r] = *(const f16x8*)&sm[1][row][sl];
    }
#pragma unroll
    for (int r = 0; r < 4; ++r)
#pragma unroll
      for (int c = 0; c < 4; ++c) {
        acc[r][c] = __builtin_amdgcn_mfma_f32_16x16x32_f16(afh[r], wfh[c],
                                                           acc[r][c], 0, 0, 0);
        if (PREC == 3) {
          acc[r][c] = __builtin_amdgcn_mfma_f32_16x16x32_f16(
              afh[r], wfl[c], acc[r][c], 0, 0, 0);
          acc[r][c] = __builtin_amdgcn_mfma_f32_16x16x32_f16(
              afl[r], wfh[c], acc[r][c], 0, 0, 0);
        }
      }
    __syncthreads();
  }

  // C/D layout: col = lane&15, row = (lane>>4)*4 + reg
  const int crow = fs << 2;
  if (PART) {
    float* Cp = C + (size_t)kb * ((size_t)(nty << 7)) * N;
#pragma unroll
    for (int r = 0; r < 4; ++r) {
      const int m0 = row0 + wr + (r << 4) + crow;
#pragma unroll
      for (int c = 0; c < 4; ++c) {
        const int n0 = col0 + wc + (c << 4) + fr;
#pragma unroll
        for (int q = 0; q < 4; ++q)
          Cp[(size_t)(m0 + q) * N + n0] = acc[r][c][q];
      }
    }
  } else if (FUSE3) {
    const int grp = col0 >> 9;  // 0:Q 1:K 2:V (128 | 512, no straddle)
    float* Cb = (grp == 0) ? C : ((grp == 1) ? C2 : C3);
#pragma unroll
    for (int r = 0; r < 4; ++r) {
      const int m0 = row0 + wr + (r << 4) + crow;
#pragma unroll
      for (int c = 0; c < 4; ++c) {
        const int n0 = col0 + wc + (c << 4) + fr;  // bias index (concat 1536)
        const int cl = n0 & 511;                   // local col, ldc = 512
        const float bcol = bias[n0];
#pragma unroll
        for (int q = 0; q < 4; ++q)
          Cb[(size_t)(m0 + q) * 512 + cl] = acc[r][c][q] + bcol;
      }
    }
  } else {
#pragma unroll
    for (int r = 0; r < 4; ++r) {
      const int m0 = row0 + wr + (r << 4) + crow;
#pragma unroll
      for (int c = 0; c < 4; ++c) {
        const int n0 = col0 + wc + (c << 4) + fr;
        const float bcol = bias[n0];
#pragma unroll
        for (int q = 0; q < 4; ++q) {
          float v = acc[r][c][q] + bcol;
          if (HASR) v += Rres[(size_t)(m0 + q) * N + n0];
          if (ACT == 1) v = gelu_f(v);
          C[(size_t)(m0 + q) * N + n0] = v;
        }
      }
    }
  }
}

// combine K-split partials: out = sum_kb part[kb] + bias (+ residual). N=512.
template <int HASR>
__global__ __launch_bounds__(256) void combine_kernel(
    const float* __restrict__ part, const float* __restrict__ bias,
    const float* Rres, float* __restrict__ Cout, size_t MN, int ks) {
  size_t gid = (size_t)blockIdx.x * 256 + threadIdx.x;
  int c = (int)(gid & 511);
  float v = 0.f;
  for (int kb = 0; kb < ks; kb++) v += part[kb * MN + gid];
  v += bias[c];
  if (HASR) v += Rres[gid];
  Cout[gid] = v;
}

// ---------------------------------------------------------------- weight split (fp32 -> f16 hi/lo planes)
// hi at o[g], lo at o[ps+g] (ps = plane stride; callers may concatenate rows)
__global__ __launch_bounds__(256) void splitw_kernel(const float* __restrict__ w,
                                                     _Float16* __restrict__ o,
                                                     int n, int ps) {
  int g = (blockIdx.x * 256 + threadIdx.x) << 2;
  if (g >= n) return;
  f32x4 f = *(const f32x4*)(w + g);
  f16x4 hv, lv;
#pragma unroll
  for (int q = 0; q < 4; ++q) {
    _Float16 h = (_Float16)f[q];
    hv[q] = h;
    lv[q] = (_Float16)(f[q] - (float)h);
  }
  *(f16x4*)(o + g) = hv;
  *(f16x4*)(o + ps + g) = lv;
}

// bias concat for fused QKV: o[0:512)=a, [512:1024)=b, [1024:1536)=c
__global__ void biascat_kernel(const float* __restrict__ a,
                               const float* __restrict__ b,
                               const float* __restrict__ c,
                               float* __restrict__ o) {
  int g = blockIdx.x * 256 + threadIdx.x;
  if (g < 512) o[g] = a[g];
  else if (g < 1024) o[g] = b[g - 512];
  else if (g < 1536) o[g] = c[g - 1024];
}

// ---------------------------------------------------------------- token conv + pos embed
__global__ void tokpe_kernel(const float* __restrict__ xe,
                             const float* __restrict__ w,
                             float* __restrict__ out, int S) {
  int gid = blockIdx.x * 256 + threadIdx.x;  // B*S*512
  int o = gid & 511;
  int bt = gid >> 9;
  int t = bt % S, b = bt / S;
  float acc = 0.f;
#pragma unroll
  for (int ww = 0; ww < 3; ww++) {
    int tt = t - 1 + ww;
    tt = (tt < 0) ? tt + S : (tt >= S ? tt - S : tt);
    const float* xr = xe + ((size_t)(b * S + tt)) * 7;
#pragma unroll
    for (int i = 0; i < 7; i++) acc += xr[i] * w[o * 21 + i * 3 + ww];
  }
  int i2 = o >> 1;
  float dv = expf((float)(2 * i2) * (-9.210340371976184f / 512.0f));
  float ang = (float)t * dv;
  acc += (o & 1) ? cosf(ang) : sinf(ang);
  out[gid] = acc;
}

// ---------------------------------------------------------------- conv weight pack (emit f16 hi/lo planes directly)
__global__ void packw_kernel(const float* __restrict__ dw,
                             _Float16* __restrict__ wp) {
  int gid = blockIdx.x * 256 + threadIdx.x;  // 512*1536
  int o = gid / 1536;
  int kk = gid - o * 1536;
  int ww = kk / 512;
  int c = kk - ww * 512;
  float v = dw[((size_t)o * 512 + c) * 3 + ww];
  _Float16 h = (_Float16)v;
  wp[gid] = h;
  wp[786432 + gid] = (_Float16)(v - (float)h);
}

// ---------------------------------------------------------------- M score
// quad-per-(b,h,t): 4 lanes split d=64 into 16 floats each (64B-contiguous per
// quad per instruction). b = blk&7 keeps batch->XCD affinity.
__global__ __launch_bounds__(256, 8) void mscore_kernel(
    const float* __restrict__ Q, const float* __restrict__ Kb,
    const int* __restrict__ idxb, float* __restrict__ Mout, int L, int U) {
  int i = blockIdx.x;        // grid = L blocks
  int b = i & 7;             // batch -> XCD
  int j = i >> 3;            // [0, L/8)
  int tid = threadIdx.x;
  int qd = tid >> 2;         // quad 0..63
  int q = tid & 3;           // lane in quad
  int h = qd & 7;            // head fastest: half-wave covers one K row fully
  int t = j * 8 + (qd >> 3);
  const float* qp = Q + ((size_t)(b * L + t)) * DMODEL + h * HD + q * 4;
  float4 qv0 = *(const float4*)(qp);
  float4 qv1 = *(const float4*)(qp + 16);
  float4 qv2 = *(const float4*)(qp + 32);
  float4 qv3 = *(const float4*)(qp + 48);
  const float* Kh = Kb + (size_t)b * L * DMODEL + h * HD + q * 4;
  const int* ip = idxb + t * U;
  float mx = -3.4e38f, sm = 0.f;
  int kr = ip[0];
  for (int jj = 0; jj < U; jj++) {
    const float* kp = Kh + (size_t)kr * DMODEL;
    float4 k0 = *(const float4*)(kp);
    float4 k1 = *(const float4*)(kp + 16);
    float4 k2 = *(const float4*)(kp + 32);
    float4 k3 = *(const float4*)(kp + 48);
    if (jj + 1 < U) kr = ip[jj + 1];
    float d = qv0.x * k0.x + qv0.y * k0.y + qv0.z * k0.z + qv0.w * k0.w +
              qv1.x * k1.x + qv1.y * k1.y + qv1.z * k1.z + qv1.w * k1.w +
              qv2.x * k2.x + qv2.y * k2.y + qv2.z * k2.z + qv2.w * k2.w +
              qv3.x * k3.x + qv3.y * k3.y + qv3.z * k3.z + qv3.w * k3.w;
    d += __shfl_xor(d, 1);
    d += __shfl_xor(d, 2);
    mx = fmaxf(mx, d);
    sm += d;
  }
  if (q == 0) Mout[(size_t)(b * 8 + h) * L + t] = mx - sm / (float)L;
}

// ---------------------------------------------------------------- top-k (per b,h), register-resident
__global__ __launch_bounds__(256) void topk_kernel(const float* __restrict__ Mv,
                                                   int* __restrict__ topb, int L,
                                                   int u) {
  __shared__ float wv_s[4];
  __shared__ int wi_s[4];
  __shared__ int best_s;
  int bh = blockIdx.x, tid = threadIdx.x;
  int lane = tid & 63, w = tid >> 6;
  int cnt = L >> 8;  // 8 / 4 / 2
  float lv[8];
  for (int i = 0; i < cnt; i++) lv[i] = Mv[(size_t)bh * L + i * 256 + tid];
  for (int r = 0; r < u; r++) {
    float bv = -3.4e38f;
    int bi = 0x7fffffff;
    for (int i = 0; i < cnt; i++) {
      if (lv[i] > bv) { bv = lv[i]; bi = i * 256 + tid; }
    }
    for (int s = 32; s > 0; s >>= 1) {
      float ov = __shfl_down(bv, s);
      int oi = __shfl_down(bi, s);
      if (ov > bv || (ov == bv && oi < bi)) { bv = ov; bi = oi; }
    }
    if (lane == 0) { wv_s[w] = bv; wi_s[w] = bi; }
    __syncthreads();
    if (tid == 0) {
      float fv = wv_s[0];
      int fi = wi_s[0];
      for (int q = 1; q < 4; q++) {
        if (wv_s[q] > fv || (wv_s[q] == fv && wi_s[q] < fi)) {
          fv = wv_s[q];
          fi = wi_s[q];
        }
      }
      best_s = fi;
      topb[bh * u + r] = fi;
    }
    __syncthreads();
    int win = best_s;
    if ((win & 255) == tid) lv[win >> 8] = -3.4e38f;
  }
}

// ---------------------------------------------------------------- gather selected q rows
__global__ void gatherq_kernel(const float* __restrict__ Q,
                               const int* __restrict__ topb,
                               float* __restrict__ qsel, int L, int u) {
  int i = blockIdx.x;  // (b*8+h)*u + r
  int bh = i / u;
  int b = bh >> 3, h = bh & 7;
  int t = topb[i];
  qsel[i * HD + threadIdx.x] =
      Q[((size_t)(b * L + t)) * DMODEL + h * HD + threadIdx.x];
}

// ---------------------------------------------------------------- mean of x rows per batch (partial)
__global__ __launch_bounds__(256) void xmean_kernel(const float* __restrict__ x,
                                                    float* __restrict__ psumx,
                                                    int L) {
  int i = blockIdx.x;  // 64: b*8+g
  int b = i >> 3, g = i & 7;
  int rows = L >> 3;
  int tid = threadIdx.x;
  const float* base = x + ((size_t)b * L + (size_t)g * rows) * DMODEL;
  float s0 = 0.f, s1 = 0.f;
  for (int t = 0; t < rows; t++) {
    s0 += base[(size_t)t * DMODEL + tid];
    s1 += base[(size_t)t * DMODEL + tid + 256];
  }
  psumx[i * DMODEL + tid] = s0;
  psumx[i * DMODEL + tid + 256] = s1;
}

// mv = xmean@Wv^T + bv ; mvWo = mv@Wo^T + bo
__global__ __launch_bounds__(256) void mvmake_kernel(
    const float* __restrict__ psumx, const float* __restrict__ Wv,
    const float* __restrict__ bv, const float* __restrict__ Wo,
    const float* __restrict__ bo, float* __restrict__ mvg,
    float* __restrict__ mvWog, int L) {
  __shared__ float xm[512];
  __shared__ float mvs[512];
  int b = blockIdx.x, tid = threadIdx.x;
  float inv = 1.0f / (float)L;
  for (int nn = 0; nn < 2; nn++) {
    int c = tid + nn * 256;
    float s = 0.f;
    for (int g = 0; g < 8; g++) s += psumx[(b * 8 + g) * DMODEL + c];
    xm[c] = s * inv;
  }
  __syncthreads();
  for (int nn = 0; nn < 2; nn++) {
    int n = tid + nn * 256;
    const float* wr = Wv + (size_t)n * 512;
    float s = bv[n];
    for (int k = 0; k < 512; k += 4) {
      float4 w4 = *(const float4*)(wr + k);
      s += xm[k] * w4.x + xm[k + 1] * w4.y + xm[k + 2] * w4.z + xm[k + 3] * w4.w;
    }
    mvs[n] = s;
    mvg[b * DMODEL + n] = s;
  }
  __syncthreads();
  for (int nn = 0; nn < 2; nn++) {
    int n = tid + nn * 256;
    const float* wr = Wo + (size_t)n * 512;
    float s = bo[n];
    for (int k = 0; k < 512; k += 4) {
      float4 w4 = *(const float4*)(wr + k);
      s += mvs[k] * w4.x + mvs[k + 1] * w4.y + mvs[k + 2] * w4.z +
           mvs[k + 3] * w4.w;
    }
    mvWog[b * DMODEL + n] = s;
  }
}

// x1 = x + mvWo[b] (broadcast)
__global__ void x1bcast_kernel(const float* __restrict__ x,
                               const float* __restrict__ mvWog,
                               float* __restrict__ x1, int L) {
  int gid = blockIdx.x * 256 + threadIdx.x;  // BL*512
  int c = gid & 511;
  int r = gid >> 9;
  int b = r / L;
  x1[gid] = x[gid] + mvWog[b * DMODEL + c];
}

// ---------------------------------------------------------------- chunked flash attention for selected rows
// nchunk = L/64 -> one 64-key tile per block; grid 64*nchunk fills the machine
// (LDS 30 KB -> 5 blocks/CU = 20 waves/CU).
__global__ __launch_bounds__(256) void attnflash_kernel(
    const float* __restrict__ qsel, const float* __restrict__ Kb,
    const float* __restrict__ Vb, float* __restrict__ pm,
    float* __restrict__ pl, float* __restrict__ pO, int L, int u, int nchunk) {
  __shared__ float qs[24][64];
  __shared__ float Kt[64][68];   // transposed K tile: Kt[d][j]
  __shared__ float Ps[24][68];   // P row per query (wave-local rows)
  int blk = blockIdx.x;          // bh*nchunk + c
  int bh = blk / nchunk;
  int c = blk - bh * nchunk;
  int b = bh >> 3, h = bh & 7;
  int cs = L / nchunk;
  int tid = threadIdx.x;
  int lane = tid & 63;
  int w = tid >> 6;
  for (int i = tid; i < u * 64; i += 256)
    qs[i >> 6][i & 63] = qsel[(size_t)bh * u * 64 + i];
  float m[6], l[6], O[6];
#pragma unroll
  for (int k = 0; k < 6; k++) { m[k] = -3.4e38f; l[k] = 0.f; O[k] = 0.f; }
  const float* Kbase = Kb + (size_t)b * L * DMODEL + h * HD;
  const float* Vbase = Vb + (size_t)b * L * DMODEL + h * HD;
  const int jrow = tid & 63;        // staging row
  const int dch = (tid >> 6) << 4;  // staging d-chunk base (0,16,32,48)
  for (int j0 = c * cs; j0 < (c + 1) * cs; j0 += 64) {
    __syncthreads();  // protect Kt (and qs on first iter)
    const float* kr = Kbase + (size_t)(j0 + jrow) * DMODEL + dch;
    float4 k0 = *(const float4*)(kr);
    float4 k1 = *(const float4*)(kr + 4);
    float4 k2 = *(const float4*)(kr + 8);
    float4 k3 = *(const float4*)(kr + 12);
#pragma unroll
    for (int q = 0; q < 4; q++) {
      Kt[dch + q][jrow] = ((float*)&k0)[q];
      Kt[dch + 4 + q][jrow] = ((float*)&k1)[q];
      Kt[dch + 8 + q][jrow] = ((float*)&k2)[q];
      Kt[dch + 12 + q][jrow] = ((float*)&k3)[q];
    }
    __syncthreads();
#pragma unroll
    for (int k = 0; k < 6; k++) {
      int qi = 4 * k + w;
      if (qi >= u) break;
      float s = 0.f;
#pragma unroll
      for (int d = 0; d < 64; d++) s += qs[qi][d] * Kt[d][lane];
      s *= 0.125f;
      float mx = s;
#pragma unroll
      for (int off = 32; off > 0; off >>= 1)
        mx = fmaxf(mx, __shfl_down(mx, off));
      mx = __shfl(mx, 0);
      float mnew = fmaxf(m[k], mx);
      float p = expf(s - mnew);
      float ps = p;
#pragma unroll
      for (int off = 32; off > 0; off >>= 1) ps += __shfl_down(ps, off);
      ps = __shfl(ps, 0);
      float alpha = expf(m[k] - mnew);
      l[k] = l[k] * alpha + ps;
      m[k] = mnew;
      O[k] *= alpha;
      Ps[qi][lane] = p;
    }
    for (int j = 0; j < 64; j += 4) {
      float v0 = Vbase[(size_t)(j0 + j) * DMODEL + lane];
      float v1 = Vbase[(size_t)(j0 + j + 1) * DMODEL + lane];
      float v2 = Vbase[(size_t)(j0 + j + 2) * DMODEL + lane];
      float v3 = Vbase[(size_t)(j0 + j + 3) * DMODEL + lane];
#pragma unroll
      for (int k = 0; k < 6; k++) {
        int qi = 4 * k + w;
        if (qi >= u) break;
        O[k] += Ps[qi][j] * v0 + Ps[qi][j + 1] * v1 + Ps[qi][j + 2] * v2 +
                Ps[qi][j + 3] * v3;
      }
    }
  }
#pragma unroll
  for (int k = 0; k < 6; k++) {
    int qi = 4 * k + w;
    if (qi < u) {
      int p = (bh * nchunk + c) * u + qi;
      if (lane == 0) { pm[p] = m[k]; pl[p] = l[k]; }
      pO[(size_t)p * 64 + lane] = O[k];
    }
  }
}

// combine chunk partials + scatter: x1[row] += (O/l - mv) @ Wo[:, h-block]^T
__global__ __launch_bounds__(256) void deltaWo_kernel(
    const float* __restrict__ pm, const float* __restrict__ pl,
    const float* __restrict__ pO, const float* __restrict__ mvg,
    const int* __restrict__ topb, const float* __restrict__ Wo, float* x1,
    int L, int u, int nchunk) {
  __shared__ float ds[64];
  int sel = blockIdx.x;  // (b*8+h)*u + qi
  int bh = sel / u;
  int qi = sel - bh * u;
  int b = bh >> 3, h = bh & 7;
  int t = topb[sel];
  int tid = threadIdx.x;
  if (tid < 64) {
    float mstar = -3.4e38f;
    for (int c = 0; c < nchunk; c++)
      mstar = fmaxf(mstar, pm[(bh * nchunk + c) * u + qi]);
    float lstar = 0.f, O = 0.f;
    for (int c = 0; c < nchunk; c++) {
      int p = (bh * nchunk + c) * u + qi;
      float wgt = expf(pm[p] - mstar);
      lstar += wgt * pl[p];
      O += wgt * pO[(size_t)p * 64 + tid];
    }
    ds[tid] = O / lstar - mvg[b * DMODEL + h * HD + tid];
  }
  __syncthreads();
  float* row = x1 + ((size_t)(b * L + t)) * DMODEL;
  for (int nn = 0; nn < 2; nn++) {
    int n = tid + nn * 256;
    const float* wr = Wo + (size_t)n * 512 + h * HD;
    float a = 0.f;
#pragma unroll
    for (int k = 0; k < 64; k += 4) {
      float4 w4 = *(const float4*)(wr + k);
      a += ds[k] * w4.x + ds[k + 1] * w4.y + ds[k + 2] * w4.z + ds[k + 3] * w4.w;
    }
    atomicAdd(row + n, a);
  }
}

// ---------------------------------------------------------------- layernorm (512 cols), wave-per-row
__global__ __launch_bounds__(256) void ln_kernel(const float* __restrict__ X,
                                                 const float* __restrict__ g,
                                                 const float* __restrict__ bta,
                                                 float* __restrict__ Y) {
  int row = blockIdx.x * 4 + (threadIdx.x >> 6);
  int lane = threadIdx.x & 63;
  size_t base = (size_t)row * DMODEL + lane * 8;
  float4 a = *(const float4*)(X + base);
  float4 b = *(const float4*)(X + base + 4);
  float s = a.x + a.y + a.z + a.w + b.x + b.y + b.z + b.w;
#pragma unroll
  for (int off = 32; off > 0; off >>= 1) s += __shfl_xor(s, off);
  float mean = s * (1.0f / 512.0f);
  float d[8];
  d[0] = a.x - mean; d[1] = a.y - mean; d[2] = a.z - mean; d[3] = a.w - mean;
  d[4] = b.x - mean; d[5] = b.y - mean; d[6] = b.z - mean; d[7] = b.w - mean;
  float q = 0.f;
#pragma unroll
  for (int i = 0; i < 8; ++i) q += d[i] * d[i];
#pragma unroll
  for (int off = 32; off > 0; off >>= 1) q += __shfl_xor(q, off);
  float inv = 1.0f / sqrtf(q * (1.0f / 512.0f) + 1e-5f);
  int col = lane * 8;
  float4 g0 = *(const float4*)(g + col);
  float4 g1 = *(const float4*)(g + col + 4);
  float4 t0 = *(const float4*)(bta + col);
  float4 t1 = *(const float4*)(bta + col + 4);
  float4 y0, y1;
  y0.x = d[0] * inv * g0.x + t0.x; y0.y = d[1] * inv * g0.y + t0.y;
  y0.z = d[2] * inv * g0.z + t0.z; y0.w = d[3] * inv * g0.w + t0.w;
  y1.x = d[4] * inv * g1.x + t1.x; y1.y = d[5] * inv * g1.y + t1.y;
  y1.z = d[6] * inv * g1.z + t1.z; y1.w = d[7] * inv * g1.w + t1.w;
  *(float4*)(Y + base) = y0;
  *(float4*)(Y + base + 4) = y1;
}

// ---------------------------------------------------------------- BN stats + pool
__global__ __launch_bounds__(256) void bnpart_kernel(const float* __restrict__ z,
                                                     float* __restrict__ psum,
                                                     float* __restrict__ psq,
                                                     int rowsPer) {
  int blk = blockIdx.x, tid = threadIdx.x;
  size_t r0 = (size_t)blk * rowsPer;
  float s0 = 0, q0 = 0, s1 = 0, q1 = 0;
  for (int r = 0; r < rowsPer; r++) {
    const float* zp = z + (r0 + r) * DMODEL;
    float a = zp[tid];
    s0 += a; q0 += a * a;
    float c = zp[tid + 256];
    s1 += c; q1 += c * c;
  }
  psum[blk * DMODEL + tid] = s0;
  psum[blk * DMODEL + tid + 256] = s1;
  psq[blk * DMODEL + tid] = q0;
  psq[blk * DMODEL + tid + 256] = q1;
}

__global__ void bnfin_kernel(const float* __restrict__ psum,
                             const float* __restrict__ psq, float* __restrict__ mu,
                             float* __restrict__ var, int nb, int Rtot) {
  int c = blockIdx.x * 256 + threadIdx.x;
  float s = 0, q = 0;
  for (int b = 0; b < nb; b++) {
    s += psum[b * DMODEL + c];
    q += psq[b * DMODEL + c];
  }
  float m = s / (float)Rtot;
  mu[c] = m;
  var[c] = fmaxf(q / (float)Rtot - m * m, 0.f);
}

__global__ void bnpool_kernel(const float* __restrict__ z,
                              const float* __restrict__ mu,
                              const float* __restrict__ var,
                              const float* __restrict__ g,
                              const float* __restrict__ bta,
                              float* __restrict__ out, int L) {
  int gid = blockIdx.x * 256 + threadIdx.x;  // B*(L/2)*512
  int c = gid & 511;
  int bt = gid >> 9;
  int L2 = L >> 1;
  int t2 = bt % L2, b = bt / L2;
  float m = mu[c];
  float inv = 1.0f / sqrtf(var[c] + 1e-5f);
  float gg = g[c], bb = bta[c];
  float best = -3.4e38f;
#pragma unroll
  for (int ww = 0; ww < 3; ww++) {
    int t = 2 * t2 - 1 + ww;
    if (t < 0 || t >= L) continue;
    float yv = (z[((size_t)(b * L + t)) * DMODEL + c] - m) * inv * gg + bb;
    yv = (yv > 0.f) ? yv : expm1f(yv);
    best = fmaxf(best, yv);
  }
  out[gid] = best;
}

// ---------------------------------------------------------------- final projection (512 -> 7)
__global__ __launch_bounds__(64) void end_kernel(const float* __restrict__ xn,
                                                 const float* __restrict__ ew,
                                                 const float* __restrict__ eb,
                                                 float* __restrict__ out) {
  __shared__ float xs[512];
  __shared__ float red[64];
  int row = blockIdx.x, tid = threadIdx.x;
#pragma unroll
  for (int i = 0; i < 8; i++) xs[tid + 64 * i] = xn[(size_t)row * DMODEL + tid + 64 * i];
  __syncthreads();
  for (int c = 0; c < 7; c++) {
    float p = 0.f;
    for (int d = tid; d < 512; d += 64) p += xs[d] * ew[c * DMODEL + d];
    red[tid] = p;
    __syncthreads();
    for (int s = 32; s > 0; s >>= 1) {
      if (tid < s) red[tid] += red[tid + s];
      __syncthreads();
    }
    if (tid == 0) out[row * 7 + c] = red[0] + eb[c];
    __syncthreads();
  }
}

// ---------------------------------------------------------------- host
extern "C" void kernel_launch(void* const* d_in, const int* in_sizes, int n_in,
                              void* d_out, int out_size, void* d_ws,
                              size_t ws_size, hipStream_t stream) {
  (void)in_sizes; (void)n_in; (void)out_size;
  const float* x_enc = (const float*)d_in[0];
  const float* tok_w = (const float*)d_in[1];
  const float* Wq = (const float*)d_in[2];
  const float* bq = (const float*)d_in[3];
  const float* Wk = (const float*)d_in[4];
  const float* bk = (const float*)d_in[5];
  const float* Wv = (const float*)d_in[6];
  const float* bv = (const float*)d_in[7];
  const float* Wo = (const float*)d_in[8];
  const float* bo = (const float*)d_in[9];
  const float* w1 = (const float*)d_in[10];
  const float* b1 = (const float*)d_in[11];
  const float* w2 = (const float*)d_in[12];
  const float* b2 = (const float*)d_in[13];
  const float* g1 = (const float*)d_in[14];
  const float* be1 = (const float*)d_in[15];
  const float* g2 = (const float*)d_in[16];
  const float* be2 = (const float*)d_in[17];
  const float* dw = (const float*)d_in[18];
  const float* db = (const float*)d_in[19];
  const float* bng = (const float*)d_in[20];
  const float* bnb = (const float*)d_in[21];
  const float* lnfg = (const float*)d_in[22];
  const float* lnfb = (const float*)d_in[23];
  const float* endw = (const float*)d_in[24];
  const float* endb = (const float*)d_in[25];
  float* out = (float*)d_out;
  char* ws = (char*)d_ws;

  const int NCHMAX = 32;  // attention key chunks (layer 0: L/64 = 32)

  // ---- arena ----
  size_t o = 0;
  float* buf0 = (float*)(ws + o); o += (size_t)16384 * 512 * 4;  // x / CH(4096x2048)
  float* qbuf = (float*)(ws + o); o += (size_t)16384 * 512 * 4;  // Q / xa
  float* kbuf = (float*)(ws + o); o += (size_t)16384 * 512 * 4;  // K / x1=z
  float* wpack = (float*)(ws + o); o += (size_t)512 * 1536 * 4;  // conv W (f16 hi/lo planes)
  float* Mb    = (float*)(ws + o); o += (size_t)64 * 2048 * 4;
  int*   idxb  = (int*)(ws + o);   o += (size_t)2048 * 24 * 4;
  int*   topb  = (int*)(ws + o);   o += 8192;
  float* qsel  = (float*)(ws + o); o += (size_t)64 * 24 * 64 * 4;
  float* mvg   = (float*)(ws + o); o += (size_t)8 * 512 * 4;
  float* mvWog = (float*)(ws + o); o += (size_t)8 * 512 * 4;
  float* psumx = (float*)(ws + o); o += (size_t)64 * 512 * 4;
  float* psum  = (float*)(ws + o); o += (size_t)128 * 512 * 4;
  float* psq   = (float*)(ws + o); o += (size_t)128 * 512 * 4;
  float* muv   = (float*)(ws + o); o += 2048;
  float* varv  = (float*)(ws + o); o += 2048;
  float* biasc = (float*)(ws + o); o += 8192;   // fused QKV bias (1536 used)
  float* pmb   = (float*)(ws + o); o += (size_t)64 * NCHMAX * 24 * 4;
  float* plb   = (float*)(ws + o); o += (size_t)64 * NCHMAX * 24 * 4;
  float* pOb   = (float*)(ws + o); o += (size_t)64 * NCHMAX * 24 * 64 * 4;
  // f16 hi/lo split weight buffers (2B * 2 planes = 4B per element)
  _Float16* w1s = (_Float16*)(ws + o); o += (size_t)2048 * 512 * 4;   // 4 MB (also QKV 3MB scratch)
  _Float16* w2s = (_Float16*)(ws + o); o += (size_t)512 * 2048 * 4;   // 4 MB
  float* partb = (float*)(ws + o); o += (size_t)4 * 4096 * 2048;  // 33.6 MB: V buffer / K-split partials
  const bool uks = (ws_size >= o);  // use K-split path only if workspace allows
  float* vbuf = partb;              // V lives here until attnflash consumes it

  const int B = 8;
  const int S = 2048;
  tokpe_kernel<<<B * S * DMODEL / 256, 256, 0, stream>>>(x_enc, tok_w, buf0, S);

  int L = S;
  const int Uarr[3] = {24, 21, 21};  // 3*ceil(ln(L)) for 2048,1024,512
  for (int l = 0; l < 3; l++) {
    int U = Uarr[l];
    int u = Uarr[l];
    int BL = B * L;
    int nty = BL >> 7;   // 128-row tiles: 128 / 64 / 32
    size_t MN = (size_t)BL * 512;
    int nch = L >> 6;    // one 64-key tile per block: 32 / 16 / 8
    idx_kernel<<<(L * U + 255) / 256, 256, 0, stream>>>(idxb, L * U, l, L - 1);

    // ---- fused QKV: one N=1536 GEMM (PREC=3, bit-identical per output) ----
    splitw_kernel<<<256, 256, 0, stream>>>(Wq + (size_t)l * 262144, w1s,
                                           262144, 786432);
    splitw_kernel<<<256, 256, 0, stream>>>(Wk + (size_t)l * 262144,
                                           w1s + 262144, 262144, 786432);
    splitw_kernel<<<256, 256, 0, stream>>>(Wv + (size_t)l * 262144,
                                           w1s + 524288, 262144, 786432);
    biascat_kernel<<<6, 256, 0, stream>>>(bq + l * 512, bk + l * 512,
                                          bv + l * 512, biasc);
    gemm128<0, 0, 0, 0, 3, 1><<<nty * 12, 256, 0, stream>>>(
        buf0, w1s, biasc, nullptr, qbuf, kbuf, vbuf, 1536, 512, 0, 12, nty,
        512, 1);

    mscore_kernel<<<L, 256, 0, stream>>>(qbuf, kbuf, idxb, Mb, L, U);
    topk_kernel<<<64, 256, 0, stream>>>(Mb, topb, L, u);
    gatherq_kernel<<<64 * u, 64, 0, stream>>>(qbuf, topb, qsel, L, u);
    xmean_kernel<<<64, 256, 0, stream>>>(buf0, psumx, L);
    mvmake_kernel<<<8, 256, 0, stream>>>(psumx, Wv + (size_t)l * 262144,
                                         bv + l * 512, Wo + (size_t)l * 262144,
                                         bo + l * 512, mvg, mvWog, L);
    attnflash_kernel<<<64 * nch, 256, 0, stream>>>(qsel, kbuf, vbuf, pmb, plb,
                                                   pOb, L, u, nch);
    // x1 = x + mvWo (into kbuf) ; += sparse delta@Wo
    x1bcast_kernel<<<(unsigned)(MN / 256), 256, 0, stream>>>(buf0, mvWog, kbuf, L);
    deltaWo_kernel<<<64 * u, 256, 0, stream>>>(pmb, plb, pOb, mvg, topb,
                                               Wo + (size_t)l * 262144, kbuf, L,
                                               u, nch);
    // xa = LN1(x1) -> qbuf
    ln_kernel<<<BL / 4, 256, 0, stream>>>(kbuf, g1 + l * 512, be1 + l * 512, qbuf);
    // FFN (PREC=1), 4096-row chunks; CH = buf0 (x dead). Residual is xa (qbuf)!
    splitw_kernel<<<1024, 256, 0, stream>>>(w1 + (size_t)l * 1048576, w1s,
                                            1048576, 1048576);
    splitw_kernel<<<1024, 256, 0, stream>>>(w2 + (size_t)l * 1048576, w2s,
                                            1048576, 1048576);
    for (int r0 = 0; r0 < BL; r0 += 4096) {
      gemm128<1, 0, 0, 0, 1, 0><<<16 * 32, 256, 0, stream>>>(
          qbuf + (size_t)r0 * 512, w1s, b1 + l * 2048, nullptr, buf0, nullptr,
          nullptr, 2048, 512, 0, 16, 32, 512, 1);
      if (uks) {
        // FFN2 K-split 4: 128 -> 512 blocks (partb free: V consumed)
        gemm128<0, 0, 0, 1, 1, 0><<<4 * 32 * 4, 256, 0, stream>>>(
            buf0, w2s, nullptr, nullptr, partb, nullptr, nullptr, 512, 2048, 0,
            4, 32, 512, 4);
        combine_kernel<1><<<4096 * 512 / 256, 256, 0, stream>>>(
            partb, b2 + l * 512, qbuf + (size_t)r0 * 512,
            kbuf + (size_t)r0 * 512, (size_t)4096 * 512, 4);
      } else {
        gemm128<0, 1, 0, 0, 1, 0><<<4 * 32, 256, 0, stream>>>(
            buf0, w2s, b2 + l * 512, qbuf + (size_t)r0 * 512,
            kbuf + (size_t)r0 * 512, nullptr, nullptr, 512, 2048, 0, 4, 32,
            2048, 1);
      }
    }
    // x = LN2(z) -> buf0
    ln_kernel<<<BL / 4, 256, 0, stream>>>(kbuf, g2 + l * 512, be2 + l * 512, buf0);

    if (l < 2) {
      packw_kernel<<<512 * 1536 / 256, 256, 0, stream>>>(
          dw + (size_t)l * 512 * 512 * 3, (_Float16*)wpack);
      int gqc = 4 * nty;
      int ksc = (gqc >= 512 || !uks) ? 1 : 2;  // conv K=1536 (PREC=1)
      if (ksc == 1) {
        gemm128<0, 0, 1, 0, 1, 0><<<gqc, 256, 0, stream>>>(
            buf0, wpack, db + l * 512, nullptr, kbuf, nullptr, nullptr, 512,
            1536, L - 1, 4, nty, 1536, 1);
      } else {
        gemm128<0, 0, 1, 1, 1, 0><<<gqc * 2, 256, 0, stream>>>(
            buf0, wpack, nullptr, nullptr, partb, nullptr, nullptr, 512, 1536,
            L - 1, 4, nty, 768, 2);
        combine_kernel<0><<<(unsigned)(MN / 256), 256, 0, stream>>>(
            partb, db + l * 512, nullptr, kbuf, MN, 2);
      }
      int nb = BL / 128;
      bnpart_kernel<<<nb, 256, 0, stream>>>(kbuf, psum, psq, 128);
      bnfin_kernel<<<2, 256, 0, stream>>>(psum, psq, muv, varv, nb, BL);
      bnpool_kernel<<<(BL / 2) * 512 / 256, 256, 0, stream>>>(
          kbuf, muv, varv, bng + l * 512, bnb + l * 512, buf0, L);
      L >>= 1;
    }
  }
  int BL = B * L;  // 4096
  ln_kernel<<<BL / 4, 256, 0, stream>>>(buf0, lnfg, lnfb, qbuf);
  end_kernel<<<BL, 64, 0, stream>>>(qbuf, endw, endb, out);
}